// Round 4
// baseline (325.830 us; speedup 1.0000x reference)
//
#include <hip/hip_runtime.h>
#include <hip/hip_fp16.h>

#define CC 256   // input channels
#define OO 256   // output channels
#define HH 64
#define WW 64
#define HWN 4096 // H*W
#define MPB 64   // pixels per block
#define KQ  64   // channels per block (K-split quarter)
#define VST 72   // val_lds row stride in halfs (144B = 9*16B: b128-aligned, 8-phase-clean)

typedef _Float16 half8 __attribute__((ext_vector_type(8)));
typedef _Float16 half2v __attribute__((ext_vector_type(2)));
typedef float f32x4 __attribute__((ext_vector_type(4)));

__device__ __forceinline__ half2v u2h(unsigned u) {
  half2v h; __builtin_memcpy(&h, &u, 4); return h;
}
__device__ __forceinline__ unsigned h2u(half2v h) {
  unsigned u; __builtin_memcpy(&u, &h, 4); return u;
}
__device__ __forceinline__ unsigned short f2h(float f) {
  _Float16 h = (_Float16)f;
  unsigned short us; __builtin_memcpy(&us, &h, 2);
  return us;
}
__device__ __forceinline__ unsigned dupu(unsigned short us) {
  return ((unsigned)us << 16) | us;
}
__device__ __forceinline__ unsigned pk2(float a, float b) {
  half2v h = {(_Float16)a, (_Float16)b};
  return h2u(h);
}

// ---------- fused prep (UNCHANGED — controlled experiment) ----------
// blocks 0..1023:  x [N,C,H,W] f32 -> xt [N,HW,C] fp16   (64c x 64hw tile via LDS)
// blocks 1024..1279: w [O,C,3,3] f32 -> wt [9][O][C] fp16
__global__ __launch_bounds__(256) void prep_kernel(
    const float* __restrict__ x, const float* __restrict__ w,
    _Float16* __restrict__ xt, _Float16* __restrict__ wt) {
  const int bid = blockIdx.x;
  const int tid = threadIdx.x;
  if (bid < 1024) {
    __shared__ float tile[64][65];   // [hw][c]
    const int n  = bid >> 8;
    const int c0 = ((bid >> 6) & 3) * 64;
    const int s0 = (bid & 63) * 64;
    {
      int r  = tid >> 2;          // channel row 0..63
      int sc = (tid & 3) * 16;    // hw start
      const float* xp = x + ((size_t)(n * CC + c0 + r)) * HWN + s0 + sc;
      float4 va = *(const float4*)(xp);
      float4 vb = *(const float4*)(xp + 4);
      float4 vc = *(const float4*)(xp + 8);
      float4 vd = *(const float4*)(xp + 12);
      tile[sc + 0][r]  = va.x;  tile[sc + 1][r]  = va.y;
      tile[sc + 2][r]  = va.z;  tile[sc + 3][r]  = va.w;
      tile[sc + 4][r]  = vb.x;  tile[sc + 5][r]  = vb.y;
      tile[sc + 6][r]  = vb.z;  tile[sc + 7][r]  = vb.w;
      tile[sc + 8][r]  = vc.x;  tile[sc + 9][r]  = vc.y;
      tile[sc + 10][r] = vc.z;  tile[sc + 11][r] = vc.w;
      tile[sc + 12][r] = vd.x;  tile[sc + 13][r] = vd.y;
      tile[sc + 14][r] = vd.z;  tile[sc + 15][r] = vd.w;
    }
    __syncthreads();
    {
      int s  = tid >> 2;          // hw row
      int cg = (tid & 3) * 16;    // c start
      uint4 u0, u1;
      u0.x = pk2(tile[s][cg + 0],  tile[s][cg + 1]);
      u0.y = pk2(tile[s][cg + 2],  tile[s][cg + 3]);
      u0.z = pk2(tile[s][cg + 4],  tile[s][cg + 5]);
      u0.w = pk2(tile[s][cg + 6],  tile[s][cg + 7]);
      u1.x = pk2(tile[s][cg + 8],  tile[s][cg + 9]);
      u1.y = pk2(tile[s][cg + 10], tile[s][cg + 11]);
      u1.z = pk2(tile[s][cg + 12], tile[s][cg + 13]);
      u1.w = pk2(tile[s][cg + 14], tile[s][cg + 15]);
      _Float16* op = xt + ((size_t)(n * HWN + s0 + s)) * CC + c0 + cg;
      *(uint4*)(op)     = u0;
      *(uint4*)(op + 8) = u1;
    }
  } else {
    __shared__ _Float16 wrow[9][264];
    const int o = bid - 1024;
    const float* wp = w + (size_t)o * (CC * 9);
    float v[9];
#pragma unroll
    for (int k = 0; k < 9; ++k) v[k] = wp[tid * 9 + k];
#pragma unroll
    for (int k = 0; k < 9; ++k) wrow[k][tid] = (_Float16)v[k];
    __syncthreads();
    for (int r = tid; r < 9 * 64; r += 256) {
      int k  = r >> 6;
      int c4 = (r & 63) * 4;
      *(uint2*)(wt + (size_t)k * (OO * CC) + (size_t)o * CC + c4) =
          *(const uint2*)(&wrow[k][c4]);
    }
  }
}

// ---------------- deform-sample + MFMA GEMM, K-SPLIT x4 ----------------
// grid 1024 x 256 thr, 4 blocks/CU, 16 waves/CU (50% occupancy at VGPR<=128).
// Block = 64 px x 256 o x 64 channels (its K quarter); out += via atomicAdd
// (out zeroed in-stream by hipMemsetAsync). No sampling duplication:
// each block reads only its 64-ch slice of each corner row (128B) ->
// sampling L2 = 295 MB total, weights 302 MB. LDS 18.5 KB/block.
// Per wave: 64 px x 64 o (wv -> o-base), mt=4, nt=4, ks=2: 32 MFMA/tap.
// XCD decode: xcd=bx&7 -> image xcd>>1, row-half xcd&1; local=bx>>3:
//   kq=local&3 (channel quarter), row=local>>2 (0..31).
// Per-XCD L2: 1 MB xt half-image + 1.18 MB wt + ~2 MB out lines < 4 MiB-ish.
__global__ __launch_bounds__(256, 4) void deform_mfma_kernel(
    const _Float16* __restrict__ xt,   // [4][4096][256] fp16
    const _Float16* __restrict__ wt,   // [9][256][256] fp16 ([k][o][c])
    const float* __restrict__ off,
    float* __restrict__ out) {
  __shared__ __align__(16) _Float16 val_lds[MPB * VST];   // 9216 B [p][c-in-quarter]
  __shared__ ushort4 s_po[MPB * 9];   // clamped flat corner row offsets (4608 B)
  __shared__ ushort4 s_pw[MPB * 9];   // fp16 bilinear weights (4608 B)

  const int tid  = threadIdx.x;
  const int lane = tid & 63;
  const int wv   = tid >> 6;
  const int n15  = lane & 15;
  const int quad = lane >> 4;

  const int bx    = blockIdx.x;
  const int xcd   = bx & 7;
  const int local = bx >> 3;                 // 0..127
  const int nb    = xcd >> 1;                // image
  const int kq    = local & 3;               // channel quarter
  const int hw0   = (((xcd & 1) << 5) | (local >> 2)) * 64;  // pixel row
  const int c0    = kq * KQ;

  // ---- precompute per-(pixel,tap) sampling params ----
  for (int e = tid; e < MPB * 9; e += 256) {
    int p = e / 9;
    int k = e - p * 9;
    int hw = hw0 + p;
    int h = hw >> 6, w = hw & 63;
    size_t ob = ((size_t)(nb * HWN + hw)) * 18 + 2 * k;
    float2 d = *(const float2*)(off + ob);
    float py = (float)(h + k / 3 - 1) + d.x;
    float px = (float)(w + k % 3 - 1) + d.y;
    float fy = floorf(py), fx = floorf(px);
    int iy = (int)fy, ix = (int)fx;
    float wy = py - fy, wx = px - fx;
    float my0 = ((unsigned)iy       < (unsigned)HH) ? 1.f : 0.f;
    float my1 = ((unsigned)(iy + 1) < (unsigned)HH) ? 1.f : 0.f;
    float mx0 = ((unsigned)ix       < (unsigned)WW) ? 1.f : 0.f;
    float mx1 = ((unsigned)(ix + 1) < (unsigned)WW) ? 1.f : 0.f;
    int iy0 = min(max(iy, 0), HH - 1), iy1 = min(max(iy + 1, 0), HH - 1);
    int ix0 = min(max(ix, 0), WW - 1), ix1 = min(max(ix + 1, 0), WW - 1);
    s_po[e] = make_ushort4((unsigned short)(iy0 * WW + ix0),
                           (unsigned short)(iy0 * WW + ix1),
                           (unsigned short)(iy1 * WW + ix0),
                           (unsigned short)(iy1 * WW + ix1));
    s_pw[e] = make_ushort4(f2h((1.f - wy) * (1.f - wx) * my0 * mx0),
                           f2h((1.f - wy) * wx         * my0 * mx1),
                           f2h(wy         * (1.f - wx) * my1 * mx0),
                           f2h(wy         * wx         * my1 * mx1));
  }

  f32x4 acc[4][4];
#pragma unroll
  for (int a = 0; a < 4; ++a)
#pragma unroll
    for (int b = 0; b < 4; ++b) acc[a][b] = (f32x4){0.f, 0.f, 0.f, 0.f};

  const _Float16* xb = xt + (size_t)nb * HWN * CC + c0;
  const int j  = lane & 7;            // channel chunk j*8..j*8+7 within quarter
  const int pl = lane >> 3;           // which of 8 pixels this lane samples

  for (int k = 0; k < 9; ++k) {
    __syncthreads();   // prev tap A-reads done; (k==0) params visible

    // ---- sample tap k: 8 pixels per wave-iter, 128B per corner-row slice ----
#pragma unroll
    for (int i = 0; i < 2; ++i) {
      int p = i * 32 + wv * 8 + pl;
      int idx = p * 9 + k;
      ushort4 o4 = s_po[idx];
      ushort4 hw4 = s_pw[idx];
      half2v w00 = u2h(dupu(hw4.x)), w01 = u2h(dupu(hw4.y));
      half2v w10 = u2h(dupu(hw4.z)), w11 = u2h(dupu(hw4.w));
      const _Float16* cb = xb + (size_t)j * 8;
      uint4 v00 = *(const uint4*)(cb + (size_t)o4.x * CC);
      uint4 v01 = *(const uint4*)(cb + (size_t)o4.y * CC);
      uint4 v10 = *(const uint4*)(cb + (size_t)o4.z * CC);
      uint4 v11 = *(const uint4*)(cb + (size_t)o4.w * CC);
      uint4 r;
      r.x = h2u(u2h(v00.x) * w00 + u2h(v01.x) * w01 + u2h(v10.x) * w10 + u2h(v11.x) * w11);
      r.y = h2u(u2h(v00.y) * w00 + u2h(v01.y) * w01 + u2h(v10.y) * w10 + u2h(v11.y) * w11);
      r.z = h2u(u2h(v00.z) * w00 + u2h(v01.z) * w01 + u2h(v10.z) * w10 + u2h(v11.z) * w11);
      r.w = h2u(u2h(v00.w) * w00 + u2h(v01.w) * w01 + u2h(v10.w) * w10 + u2h(v11.w) * w11);
      *(uint4*)(val_lds + p * VST + j * 8) = r;
    }
    __syncthreads();   // val_lds staged for tap k

    // ---- GEMM tap k: A from LDS, B from L2-resident wt ----
    const _Float16* wb = wt + ((size_t)(k * OO + wv * 64)) * CC + c0;
#pragma unroll
    for (int ks = 0; ks < 2; ++ks) {
      half8 afr[4], bfr[4];
#pragma unroll
      for (int mt = 0; mt < 4; ++mt)
        afr[mt] = *(const half8*)(val_lds + (mt * 16 + n15) * VST + ks * 32 + quad * 8);
#pragma unroll
      for (int nt = 0; nt < 4; ++nt)
        bfr[nt] = *(const half8*)(wb + (size_t)(nt * 16 + n15) * CC + ks * 32 + quad * 8);
#pragma unroll
      for (int mt = 0; mt < 4; ++mt)
#pragma unroll
        for (int nt = 0; nt < 4; ++nt)
          acc[mt][nt] = __builtin_amdgcn_mfma_f32_16x16x32_f16(
              afr[mt], bfr[nt], acc[mt][nt], 0, 0, 0);
    }
  }

  // ---- epilogue: atomic accumulate K-quarter partials ----
  // D: col=lane&15 -> o, row=quad*4+reg -> pixel
#pragma unroll
  for (int mt = 0; mt < 4; ++mt)
#pragma unroll
    for (int nt = 0; nt < 4; ++nt) {
      int o  = wv * 64 + nt * 16 + n15;
      int px = hw0 + mt * 16 + quad * 4;
      float* dst = out + ((size_t)nb * OO + o) * HWN + px;
      atomicAdd(dst + 0, acc[mt][nt].x);
      atomicAdd(dst + 1, acc[mt][nt].y);
      atomicAdd(dst + 2, acc[mt][nt].z);
      atomicAdd(dst + 3, acc[mt][nt].w);
    }
}

extern "C" void kernel_launch(void* const* d_in, const int* in_sizes, int n_in,
                              void* d_out, int out_size, void* d_ws, size_t ws_size,
                              hipStream_t stream) {
  const float* x   = (const float*)d_in[0];   // [4,256,64,64]
  const float* off = (const float*)d_in[1];   // [4,4096,18]
  const float* w   = (const float*)d_in[2];   // [256,256,3,3]
  float* out = (float*)d_out;                 // [4,256,64,64]

  _Float16* wt = (_Float16*)d_ws;             // 589824 fp16
  _Float16* xt = wt + 589824;                 // 4194304 fp16

  hipMemsetAsync(d_out, 0, (size_t)4 * OO * HWN * sizeof(float), stream);
  prep_kernel<<<1024 + 256, 256, 0, stream>>>(x, w, xt, wt);
  deform_mfma_kernel<<<1024, 256, 0, stream>>>(xt, wt, off, out);
}

// Round 5
// 174.810 us; speedup vs baseline: 1.8639x; 1.8639x over previous
//
#include <hip/hip_runtime.h>
#include <hip/hip_fp16.h>

#define CC 256   // input channels
#define OO 256   // output channels
#define HH 64
#define WW 64
#define HWN 4096 // H*W
#define MPB 32   // pixels per block
#define VST 264  // val_lds row stride (halfs)
#define WST 44   // w_lds row stride (halfs): 88B -> start banks spread, min-achieving
#define WBUF (256 * WST)   // halfs per weight buffer

typedef _Float16 half8 __attribute__((ext_vector_type(8)));
typedef _Float16 half2v __attribute__((ext_vector_type(2)));
typedef float f32x4 __attribute__((ext_vector_type(4)));

__device__ __forceinline__ half2v u2h(unsigned u) {
  half2v h; __builtin_memcpy(&h, &u, 4); return h;
}
__device__ __forceinline__ unsigned h2u(half2v h) {
  unsigned u; __builtin_memcpy(&u, &h, 4); return u;
}
__device__ __forceinline__ unsigned short f2h(float f) {
  _Float16 h = (_Float16)f;
  unsigned short us; __builtin_memcpy(&us, &h, 2);
  return us;
}
__device__ __forceinline__ unsigned dupu(unsigned short us) {
  return ((unsigned)us << 16) | us;
}
__device__ __forceinline__ unsigned pk2(float a, float b) {
  half2v h = {(_Float16)a, (_Float16)b};
  return h2u(h);
}

// ---------- fused prep (UNCHANGED — controlled experiment) ----------
// blocks 0..1023:  x [N,C,H,W] f32 -> xt [N,HW,C] fp16   (64c x 64hw tile via LDS)
// blocks 1024..1279: w [O,C,3,3] f32 -> wt [9][O][C] fp16
__global__ __launch_bounds__(256) void prep_kernel(
    const float* __restrict__ x, const float* __restrict__ w,
    _Float16* __restrict__ xt, _Float16* __restrict__ wt) {
  const int bid = blockIdx.x;
  const int tid = threadIdx.x;
  if (bid < 1024) {
    __shared__ float tile[64][65];   // [hw][c]
    const int n  = bid >> 8;
    const int c0 = ((bid >> 6) & 3) * 64;
    const int s0 = (bid & 63) * 64;
    {
      int r  = tid >> 2;          // channel row 0..63
      int sc = (tid & 3) * 16;    // hw start
      const float* xp = x + ((size_t)(n * CC + c0 + r)) * HWN + s0 + sc;
      float4 va = *(const float4*)(xp);
      float4 vb = *(const float4*)(xp + 4);
      float4 vc = *(const float4*)(xp + 8);
      float4 vd = *(const float4*)(xp + 12);
      tile[sc + 0][r]  = va.x;  tile[sc + 1][r]  = va.y;
      tile[sc + 2][r]  = va.z;  tile[sc + 3][r]  = va.w;
      tile[sc + 4][r]  = vb.x;  tile[sc + 5][r]  = vb.y;
      tile[sc + 6][r]  = vb.z;  tile[sc + 7][r]  = vb.w;
      tile[sc + 8][r]  = vc.x;  tile[sc + 9][r]  = vc.y;
      tile[sc + 10][r] = vc.z;  tile[sc + 11][r] = vc.w;
      tile[sc + 12][r] = vd.x;  tile[sc + 13][r] = vd.y;
      tile[sc + 14][r] = vd.z;  tile[sc + 15][r] = vd.w;
    }
    __syncthreads();
    {
      int s  = tid >> 2;          // hw row
      int cg = (tid & 3) * 16;    // c start
      uint4 u0, u1;
      u0.x = pk2(tile[s][cg + 0],  tile[s][cg + 1]);
      u0.y = pk2(tile[s][cg + 2],  tile[s][cg + 3]);
      u0.z = pk2(tile[s][cg + 4],  tile[s][cg + 5]);
      u0.w = pk2(tile[s][cg + 6],  tile[s][cg + 7]);
      u1.x = pk2(tile[s][cg + 8],  tile[s][cg + 9]);
      u1.y = pk2(tile[s][cg + 10], tile[s][cg + 11]);
      u1.z = pk2(tile[s][cg + 12], tile[s][cg + 13]);
      u1.w = pk2(tile[s][cg + 14], tile[s][cg + 15]);
      _Float16* op = xt + ((size_t)(n * HWN + s0 + s)) * CC + c0 + cg;
      *(uint4*)(op)     = u0;
      *(uint4*)(op + 8) = u1;
    }
  } else {
    __shared__ _Float16 wrow[9][264];
    const int o = bid - 1024;
    const float* wp = w + (size_t)o * (CC * 9);
    float v[9];
#pragma unroll
    for (int k = 0; k < 9; ++k) v[k] = wp[tid * 9 + k];
#pragma unroll
    for (int k = 0; k < 9; ++k) wrow[k][tid] = (_Float16)v[k];
    __syncthreads();
    for (int r = tid; r < 9 * 64; r += 256) {
      int k  = r >> 6;
      int c4 = (r & 63) * 4;
      *(uint2*)(wt + (size_t)k * (OO * CC) + (size_t)o * CC + c4) =
          *(const uint2*)(&wrow[k][c4]);
    }
  }
}

// ---------------- deform-sample + MFMA GEMM: full-O blocks, 2 blocks/CU ----------------
// grid 512 x 512 thr (8 waves). Block: 32 px x 256 o x 256 c.
// 2 blocks/CU -> 16 waves/CU (50% occ at VGPR<=128): two independent
// barrier-groups per CU so one block's GEMM hides the other's sampling latency.
// No o-split: sampling L2 traffic = 295 MB (halved); weights staged per-32c
// slice into double-buffered LDS (B from ds_read — the only B path that worked).
// Each output written exactly once (no atomics).
// Waves: o-quarter = wv&3 (64 o), px-half = wv>>2 (16 px); nt=4, ks=8 -> 32 MFMA/tap.
// XCD decode: xcd=bx&7 -> image xcd>>1, img-half xcd&1; group = bx>>3 (0..63).
// Per-XCD L2: ~1 MB xt half-image + 1.18 MB wt < 4 MiB.
__global__ __launch_bounds__(512, 4) void deform_mfma_kernel(
    const _Float16* __restrict__ xt,   // [4][4096][256] fp16
    const _Float16* __restrict__ wt,   // [9][256][256] fp16 ([k][o][c])
    const float* __restrict__ off,
    float* __restrict__ out) {
  __shared__ __align__(16) _Float16 val_lds[MPB * VST];   // 16896 B [p][c]
  __shared__ __align__(16) _Float16 w_lds[2 * WBUF];      // 45056 B [buf][o][c-slice]
  __shared__ ushort4 s_po[MPB * 9];   // clamped flat corner row offsets (2304 B)
  __shared__ ushort4 s_pw[MPB * 9];   // fp16 bilinear weights (2304 B)

  const int tid  = threadIdx.x;
  const int lane = tid & 63;
  const int wv   = tid >> 6;          // 0..7
  const int n15  = lane & 15;
  const int quad = lane >> 4;

  const int bx  = blockIdx.x;
  const int xcd = bx & 7;
  const int nb  = xcd >> 1;                            // image
  const int hw0 = ((((xcd & 1) << 6) + (bx >> 3))) * MPB;  // pixel group base

  const int o0 = (wv & 3) * 64;       // wave's o-quarter
  const int p0 = (wv >> 2) * 16;      // wave's pixel half

  // ---- precompute per-(pixel,tap) sampling params (288 entries, single pass) ----
  if (tid < MPB * 9) {
    int e = tid;
    int p = e / 9;
    int k = e - p * 9;
    int hw = hw0 + p;
    int h = hw >> 6, w = hw & 63;
    size_t ob = ((size_t)(nb * HWN + hw)) * 18 + 2 * k;
    float2 d = *(const float2*)(off + ob);
    float py = (float)(h + k / 3 - 1) + d.x;
    float px = (float)(w + k % 3 - 1) + d.y;
    float fy = floorf(py), fx = floorf(px);
    int iy = (int)fy, ix = (int)fx;
    float wy = py - fy, wx = px - fx;
    float my0 = ((unsigned)iy       < (unsigned)HH) ? 1.f : 0.f;
    float my1 = ((unsigned)(iy + 1) < (unsigned)HH) ? 1.f : 0.f;
    float mx0 = ((unsigned)ix       < (unsigned)WW) ? 1.f : 0.f;
    float mx1 = ((unsigned)(ix + 1) < (unsigned)WW) ? 1.f : 0.f;
    int iy0 = min(max(iy, 0), HH - 1), iy1 = min(max(iy + 1, 0), HH - 1);
    int ix0 = min(max(ix, 0), WW - 1), ix1 = min(max(ix + 1, 0), WW - 1);
    s_po[e] = make_ushort4((unsigned short)(iy0 * WW + ix0),
                           (unsigned short)(iy0 * WW + ix1),
                           (unsigned short)(iy1 * WW + ix0),
                           (unsigned short)(iy1 * WW + ix1));
    s_pw[e] = make_ushort4(f2h((1.f - wy) * (1.f - wx) * my0 * mx0),
                           f2h((1.f - wy) * wx         * my0 * mx1),
                           f2h(wy         * (1.f - wx) * my1 * mx0),
                           f2h(wy         * wx         * my1 * mx1));
  }

  f32x4 acc[4];
#pragma unroll
  for (int b = 0; b < 4; ++b) acc[b] = (f32x4){0.f, 0.f, 0.f, 0.f};

  const _Float16* xb = xt + (size_t)nb * HWN * CC;
  const int j    = tid & 31;          // channel chunk j*8..j*8+7
  const int slot = tid >> 5;          // pixel slot 0..15
  const int so   = tid >> 1;          // weight-stage o row
  const int sh   = tid & 1;           // weight-stage half (16 halfs)

  for (int k = 0; k < 9; ++k) {
    __syncthreads();   // (a) prev tap's A/B reads done; val_lds & wbuf0 writable

    // ---- sample tap k: 2 pixels per thread, contiguous 512B rows per pixel ----
#pragma unroll
    for (int i = 0; i < 2; ++i) {
      int p = i * 16 + slot;
      int idx = p * 9 + k;
      ushort4 o4 = s_po[idx];
      ushort4 hw4 = s_pw[idx];
      half2v w00 = u2h(dupu(hw4.x)), w01 = u2h(dupu(hw4.y));
      half2v w10 = u2h(dupu(hw4.z)), w11 = u2h(dupu(hw4.w));
      const _Float16* cb = xb + (size_t)j * 8;
      uint4 v00 = *(const uint4*)(cb + (size_t)o4.x * CC);
      uint4 v01 = *(const uint4*)(cb + (size_t)o4.y * CC);
      uint4 v10 = *(const uint4*)(cb + (size_t)o4.z * CC);
      uint4 v11 = *(const uint4*)(cb + (size_t)o4.w * CC);
      uint4 r;
      r.x = h2u(u2h(v00.x) * w00 + u2h(v01.x) * w01 + u2h(v10.x) * w10 + u2h(v11.x) * w11);
      r.y = h2u(u2h(v00.y) * w00 + u2h(v01.y) * w01 + u2h(v10.y) * w10 + u2h(v11.y) * w11);
      r.z = h2u(u2h(v00.z) * w00 + u2h(v01.z) * w01 + u2h(v10.z) * w10 + u2h(v11.z) * w11);
      r.w = h2u(u2h(v00.w) * w00 + u2h(v01.w) * w01 + u2h(v10.w) * w10 + u2h(v11.w) * w11);
      *(uint4*)(val_lds + p * VST + j * 8) = r;
    }

    // ---- stage weights slice ks=0 into buf0 (32B/thread, coalesced 64B per o) ----
    {
      const uint4* src = (const uint4*)(wt + ((size_t)(k * OO + so)) * CC + sh * 16);
      uint4* dst = (uint4*)(w_lds + so * WST + sh * 16);
      dst[0] = src[0];
      dst[1] = src[1];
    }
    __syncthreads();   // (b) val_lds + wbuf0 ready

    // ---- GEMM tap k over 8 x 32-channel slices, double-buffered B ----
#pragma unroll
    for (int ks = 0; ks < 8; ++ks) {
      const int cur = ks & 1;
      if (ks < 7) {   // stage next slice into the other buffer (loads issue early)
        const uint4* src = (const uint4*)(wt + ((size_t)(k * OO + so)) * CC + (ks + 1) * 32 + sh * 16);
        uint4* dst = (uint4*)(w_lds + (cur ^ 1) * WBUF + so * WST + sh * 16);
        dst[0] = src[0];
        dst[1] = src[1];
      }
      half8 afr = *(const half8*)(val_lds + (p0 + n15) * VST + ks * 32 + quad * 8);
      half8 bfr[4];
#pragma unroll
      for (int nt = 0; nt < 4; ++nt)
        bfr[nt] = *(const half8*)(w_lds + cur * WBUF + (o0 + nt * 16 + n15) * WST + quad * 8);
#pragma unroll
      for (int nt = 0; nt < 4; ++nt)
        acc[nt] = __builtin_amdgcn_mfma_f32_16x16x32_f16(afr, bfr[nt], acc[nt], 0, 0, 0);
      if (ks < 7) __syncthreads();   // (c) staged buf visible; cur reads done
    }
  }

  // ---- epilogue: D: col=lane&15 -> o, row=quad*4+reg -> pixel ----
#pragma unroll
  for (int nt = 0; nt < 4; ++nt) {
    int o  = o0 + nt * 16 + n15;
    int px = hw0 + p0 + quad * 4;
    *(f32x4*)(out + ((size_t)nb * OO + o) * HWN + px) = acc[nt];
  }
}

extern "C" void kernel_launch(void* const* d_in, const int* in_sizes, int n_in,
                              void* d_out, int out_size, void* d_ws, size_t ws_size,
                              hipStream_t stream) {
  const float* x   = (const float*)d_in[0];   // [4,256,64,64]
  const float* off = (const float*)d_in[1];   // [4,4096,18]
  const float* w   = (const float*)d_in[2];   // [256,256,3,3]
  float* out = (float*)d_out;                 // [4,256,64,64]

  _Float16* wt = (_Float16*)d_ws;             // 589824 fp16
  _Float16* xt = wt + 589824;                 // 4194304 fp16

  prep_kernel<<<1024 + 256, 256, 0, stream>>>(x, w, xt, wt);
  deform_mfma_kernel<<<512, 512, 0, stream>>>(xt, wt, off, out);
}

// Round 6
// 152.604 us; speedup vs baseline: 2.1351x; 1.1455x over previous
//
#include <hip/hip_runtime.h>
#include <hip/hip_fp16.h>

#define CC 256   // input channels
#define OO 256   // output channels
#define HH 64
#define WW 64
#define HWN 4096 // H*W
#define MPB 32   // pixels per block
#define VST 264  // val_lds row stride in halfs (528B = 33*16B: odd 16B-stride -> 2-way banks)

typedef _Float16 half8 __attribute__((ext_vector_type(8)));
typedef _Float16 half2v __attribute__((ext_vector_type(2)));
typedef float f32x4 __attribute__((ext_vector_type(4)));

__device__ __forceinline__ half2v u2h(unsigned u) {
  half2v h; __builtin_memcpy(&h, &u, 4); return h;
}
__device__ __forceinline__ unsigned h2u(half2v h) {
  unsigned u; __builtin_memcpy(&u, &h, 4); return u;
}
__device__ __forceinline__ unsigned short f2h(float f) {
  _Float16 h = (_Float16)f;
  unsigned short us; __builtin_memcpy(&us, &h, 2);
  return us;
}
__device__ __forceinline__ unsigned dupu(unsigned short us) {
  return ((unsigned)us << 16) | us;
}
__device__ __forceinline__ unsigned pk2(float a, float b) {
  half2v h = {(_Float16)a, (_Float16)b};
  return h2u(h);
}

// raw barrier: NO vmcnt drain (in-flight global loads survive); explicit lgkm
// wait orders ds_write->barrier->ds_read; sched_barriers pin code motion (rule 18).
__device__ __forceinline__ void vsync() {
  __builtin_amdgcn_sched_barrier(0);
  asm volatile("s_waitcnt lgkmcnt(0)" ::: "memory");
  __builtin_amdgcn_s_barrier();
  __builtin_amdgcn_sched_barrier(0);
}

// ---------- fused prep (UNCHANGED — controlled experiment) ----------
// blocks 0..1023:  x [N,C,H,W] f32 -> xt [N,HW,C] fp16   (64c x 64hw tile via LDS)
// blocks 1024..1279: w [O,C,3,3] f32 -> wt [9][O][C] fp16
__global__ __launch_bounds__(256) void prep_kernel(
    const float* __restrict__ x, const float* __restrict__ w,
    _Float16* __restrict__ xt, _Float16* __restrict__ wt) {
  const int bid = blockIdx.x;
  const int tid = threadIdx.x;
  if (bid < 1024) {
    __shared__ float tile[64][65];   // [hw][c]
    const int n  = bid >> 8;
    const int c0 = ((bid >> 6) & 3) * 64;
    const int s0 = (bid & 63) * 64;
    {
      int r  = tid >> 2;          // channel row 0..63
      int sc = (tid & 3) * 16;    // hw start
      const float* xp = x + ((size_t)(n * CC + c0 + r)) * HWN + s0 + sc;
      float4 va = *(const float4*)(xp);
      float4 vb = *(const float4*)(xp + 4);
      float4 vc = *(const float4*)(xp + 8);
      float4 vd = *(const float4*)(xp + 12);
      tile[sc + 0][r]  = va.x;  tile[sc + 1][r]  = va.y;
      tile[sc + 2][r]  = va.z;  tile[sc + 3][r]  = va.w;
      tile[sc + 4][r]  = vb.x;  tile[sc + 5][r]  = vb.y;
      tile[sc + 6][r]  = vb.z;  tile[sc + 7][r]  = vb.w;
      tile[sc + 8][r]  = vc.x;  tile[sc + 9][r]  = vc.y;
      tile[sc + 10][r] = vc.z;  tile[sc + 11][r] = vc.w;
      tile[sc + 12][r] = vd.x;  tile[sc + 13][r] = vd.y;
      tile[sc + 14][r] = vd.z;  tile[sc + 15][r] = vd.w;
    }
    __syncthreads();
    {
      int s  = tid >> 2;          // hw row
      int cg = (tid & 3) * 16;    // c start
      uint4 u0, u1;
      u0.x = pk2(tile[s][cg + 0],  tile[s][cg + 1]);
      u0.y = pk2(tile[s][cg + 2],  tile[s][cg + 3]);
      u0.z = pk2(tile[s][cg + 4],  tile[s][cg + 5]);
      u0.w = pk2(tile[s][cg + 6],  tile[s][cg + 7]);
      u1.x = pk2(tile[s][cg + 8],  tile[s][cg + 9]);
      u1.y = pk2(tile[s][cg + 10], tile[s][cg + 11]);
      u1.z = pk2(tile[s][cg + 12], tile[s][cg + 13]);
      u1.w = pk2(tile[s][cg + 14], tile[s][cg + 15]);
      _Float16* op = xt + ((size_t)(n * HWN + s0 + s)) * CC + c0 + cg;
      *(uint4*)(op)     = u0;
      *(uint4*)(op + 8) = u1;
    }
  } else {
    __shared__ _Float16 wrow[9][264];
    const int o = bid - 1024;
    const float* wp = w + (size_t)o * (CC * 9);
    float v[9];
#pragma unroll
    for (int k = 0; k < 9; ++k) v[k] = wp[tid * 9 + k];
#pragma unroll
    for (int k = 0; k < 9; ++k) wrow[k][tid] = (_Float16)v[k];
    __syncthreads();
    for (int r = tid; r < 9 * 64; r += 256) {
      int k  = r >> 6;
      int c4 = (r & 63) * 4;
      *(uint2*)(wt + (size_t)k * (OO * CC) + (size_t)o * CC + c4) =
          *(const uint2*)(&wrow[k][c4]);
    }
  }
}

// ---------------- deform-sample + MFMA GEMM: full-O, B-in-registers ----------------
// grid 512 x 512 thr (8 waves). Block: 32 px x 256 o x 256 c; wave = 32px x 32o.
// B fragments load DIRECTLY from L2-resident wt into registers (16 x b128/wave/tap)
// -- each B element was read exactly once per wave anyway (zero cross-wave reuse),
// so w_lds + its 27 staging barriers are pure overhead. 2 raw barriers/tap, no
// vmcnt drains at barriers. LDS = 21.5 KB -> 2 blocks/CU = 16 waves/CU
// (two independent barrier domains: one block's GEMM hides the other's sampling).
// L2 traffic: samples 302 MB (full-O, no dup) + B 604 MB = ~906 MB.
// XCD decode: xcd=bx&7 -> image xcd>>1, img-half xcd&1; group bx>>3 (0..63).
// Per-XCD L2 set: 1 MB xt half-image + 1.18 MB wt < 4 MiB.
__global__ __launch_bounds__(512, 4) void deform_mfma_kernel(
    const _Float16* __restrict__ xt,   // [4][4096][256] fp16
    const _Float16* __restrict__ wt,   // [9][256][256] fp16 ([k][o][c])
    const float* __restrict__ off,
    float* __restrict__ out) {
  __shared__ __align__(16) _Float16 val_lds[MPB * VST];   // 16896 B [p][c]
  __shared__ ushort4 s_po[MPB * 9];   // clamped flat corner row offsets (2304 B)
  __shared__ ushort4 s_pw[MPB * 9];   // fp16 bilinear weights (2304 B)

  const int tid  = threadIdx.x;
  const int lane = tid & 63;
  const int wv   = tid >> 6;          // 0..7 -> o-slice wv*32
  const int n15  = lane & 15;
  const int quad = lane >> 4;

  const int bx  = blockIdx.x;
  const int xcd = bx & 7;
  const int nb  = xcd >> 1;                              // image
  const int hw0 = (((xcd & 1) << 6) | (bx >> 3)) * MPB;  // pixel group base

  const int o0 = wv * 32;             // wave's o-slice

  // ---- precompute per-(pixel,tap) sampling params (288 entries) ----
  if (tid < MPB * 9) {
    int e = tid;
    int p = e / 9;
    int k = e - p * 9;
    int hw = hw0 + p;
    int h = hw >> 6, w = hw & 63;
    size_t ob = ((size_t)(nb * HWN + hw)) * 18 + 2 * k;
    float2 d = *(const float2*)(off + ob);
    float py = (float)(h + k / 3 - 1) + d.x;
    float px = (float)(w + k % 3 - 1) + d.y;
    float fy = floorf(py), fx = floorf(px);
    int iy = (int)fy, ix = (int)fx;
    float wy = py - fy, wx = px - fx;
    float my0 = ((unsigned)iy       < (unsigned)HH) ? 1.f : 0.f;
    float my1 = ((unsigned)(iy + 1) < (unsigned)HH) ? 1.f : 0.f;
    float mx0 = ((unsigned)ix       < (unsigned)WW) ? 1.f : 0.f;
    float mx1 = ((unsigned)(ix + 1) < (unsigned)WW) ? 1.f : 0.f;
    int iy0 = min(max(iy, 0), HH - 1), iy1 = min(max(iy + 1, 0), HH - 1);
    int ix0 = min(max(ix, 0), WW - 1), ix1 = min(max(ix + 1, 0), WW - 1);
    s_po[e] = make_ushort4((unsigned short)(iy0 * WW + ix0),
                           (unsigned short)(iy0 * WW + ix1),
                           (unsigned short)(iy1 * WW + ix0),
                           (unsigned short)(iy1 * WW + ix1));
    s_pw[e] = make_ushort4(f2h((1.f - wy) * (1.f - wx) * my0 * mx0),
                           f2h((1.f - wy) * wx         * my0 * mx1),
                           f2h(wy         * (1.f - wx) * my1 * mx0),
                           f2h(wy         * wx         * my1 * mx1));
  }

  f32x4 acc[2][2];
#pragma unroll
  for (int a = 0; a < 2; ++a)
#pragma unroll
    for (int b = 0; b < 2; ++b) acc[a][b] = (f32x4){0.f, 0.f, 0.f, 0.f};

  const _Float16* xb = xt + (size_t)nb * HWN * CC;
  const int j    = tid & 31;          // channel chunk j*8..j*8+7
  const int slot = tid >> 5;          // pixel slot 0..15

  // sample one tap: 512 thr cover 32 px x 256 c in 2 passes; load+combine+write
  auto sample_tap = [&](int kk) {
#pragma unroll
    for (int i = 0; i < 2; ++i) {
      int p = i * 16 + slot;
      int idx = p * 9 + kk;
      ushort4 o4 = s_po[idx];
      ushort4 hw4 = s_pw[idx];
      half2v w00 = u2h(dupu(hw4.x)), w01 = u2h(dupu(hw4.y));
      half2v w10 = u2h(dupu(hw4.z)), w11 = u2h(dupu(hw4.w));
      const _Float16* cb = xb + (size_t)j * 8;
      uint4 v00 = *(const uint4*)(cb + (size_t)o4.x * CC);
      uint4 v01 = *(const uint4*)(cb + (size_t)o4.y * CC);
      uint4 v10 = *(const uint4*)(cb + (size_t)o4.z * CC);
      uint4 v11 = *(const uint4*)(cb + (size_t)o4.w * CC);
      uint4 r;
      r.x = h2u(u2h(v00.x) * w00 + u2h(v01.x) * w01 + u2h(v10.x) * w10 + u2h(v11.x) * w11);
      r.y = h2u(u2h(v00.y) * w00 + u2h(v01.y) * w01 + u2h(v10.y) * w10 + u2h(v11.y) * w11);
      r.z = h2u(u2h(v00.z) * w00 + u2h(v01.z) * w01 + u2h(v10.z) * w10 + u2h(v11.z) * w11);
      r.w = h2u(u2h(v00.w) * w00 + u2h(v01.w) * w01 + u2h(v10.w) * w10 + u2h(v11.w) * w11);
      *(uint4*)(val_lds + p * VST + j * 8) = r;
    }
  };

  __syncthreads();          // params visible (normal barrier: nothing in flight yet)
  sample_tap(0);            // prologue: tap 0 into val_lds
  vsync();                  // val[0] visible

  for (int k = 0; k < 9; ++k) {
    // ---- load this tap's B fragments straight from L2 into registers ----
    const _Float16* wb = wt + ((size_t)(k * OO + o0)) * CC;
    half8 bfr[2][8];
#pragma unroll
    for (int nt = 0; nt < 2; ++nt)
#pragma unroll
      for (int ksg = 0; ksg < 8; ++ksg)
        bfr[nt][ksg] = *(const half8*)(wb + (size_t)(nt * 16 + n15) * CC + ksg * 32 + quad * 8);
    __builtin_amdgcn_sched_barrier(0);   // pin B issue before the GEMM

    // ---- GEMM tap k: A from LDS (compiler-scheduled ds_reads cover B latency) ----
#pragma unroll
    for (int ksg = 0; ksg < 8; ++ksg) {
      half8 afr[2];
#pragma unroll
      for (int mt = 0; mt < 2; ++mt)
        afr[mt] = *(const half8*)(val_lds + (mt * 16 + n15) * VST + ksg * 32 + quad * 8);
#pragma unroll
      for (int mt = 0; mt < 2; ++mt)
#pragma unroll
        for (int nt = 0; nt < 2; ++nt)
          acc[mt][nt] = __builtin_amdgcn_mfma_f32_16x16x32_f16(
              afr[mt], bfr[nt][ksg], acc[mt][nt], 0, 0, 0);
    }

    vsync();                // all val[k] reads done -> val writable
    if (k < 8) sample_tap(k + 1);
    vsync();                // val[k+1] visible
  }

  // ---- epilogue: D: col=lane&15 -> o, row=quad*4+reg -> pixel ----
#pragma unroll
  for (int mt = 0; mt < 2; ++mt)
#pragma unroll
    for (int nt = 0; nt < 2; ++nt) {
      int o  = o0 + nt * 16 + n15;
      int px = hw0 + mt * 16 + quad * 4;
      *(f32x4*)(out + ((size_t)nb * OO + o) * HWN + px) = acc[mt][nt];
    }
}

extern "C" void kernel_launch(void* const* d_in, const int* in_sizes, int n_in,
                              void* d_out, int out_size, void* d_ws, size_t ws_size,
                              hipStream_t stream) {
  const float* x   = (const float*)d_in[0];   // [4,256,64,64]
  const float* off = (const float*)d_in[1];   // [4,4096,18]
  const float* w   = (const float*)d_in[2];   // [256,256,3,3]
  float* out = (float*)d_out;                 // [4,256,64,64]

  _Float16* wt = (_Float16*)d_ws;             // 589824 fp16
  _Float16* xt = wt + 589824;                 // 4194304 fp16

  prep_kernel<<<1024 + 256, 256, 0, stream>>>(x, w, xt, wt);
  deform_mfma_kernel<<<512, 512, 0, stream>>>(xt, wt, off, out);
}